// Round 1
// baseline (942.280 us; speedup 1.0000x reference)
//
#include <hip/hip_runtime.h>
#include <hip/hip_bf16.h>

#define NROWS 400000
#define DDIM  512
#define NSEG  50000

typedef __bf16 bf16x8 __attribute__((ext_vector_type(8)));
typedef __bf16 bf16x4 __attribute__((ext_vector_type(4)));
typedef float  f32x4_t __attribute__((ext_vector_type(4)));

// One-time: Wm [K=512][N=512] fp32  ->  WmT [N][K] bf16 (coalesced writes)
__global__ void prep_wmT(const float* __restrict__ Wm, __bf16* __restrict__ WmT) {
    int o = blockIdx.x * 256 + threadIdx.x;   // 0 .. 512*512-1, o = n*512 + k
    int n = o >> 9;
    int k = o & 511;
    WmT[o] = (__bf16)Wm[k * 512 + n];
}

// Fused: bf16 GEMM (x @ Wm), gate = exp(x . Wg + bg), scatter-accumulate
// out[idx[r]] += e_r * m_r  and  gsum[idx[r]] += e_r  (ntile==0 only).
__global__ __launch_bounds__(256)
void fused_gemm(const float* __restrict__ x,
                const int* __restrict__ idx,
                const float* __restrict__ Wg,
                const float* __restrict__ bgp,
                const __bf16* __restrict__ WmT,
                float* __restrict__ out,
                float* __restrict__ gsum) {
    __shared__ __align__(16) __bf16 As[128 * 64];
    __shared__ __align__(16) __bf16 Bs[128 * 64];
    __shared__ float gpart[128];

    const int t     = threadIdx.x;
    const int lane  = t & 63;
    const int w     = t >> 6;          // wave 0..3
    const int bid   = blockIdx.x;
    const int ntile = bid & 3;         // column tile fastest -> A-tile L2/L3 reuse
    const int mtile = bid >> 2;

    const int kq = lane & 15;          // 0..15
    const int rq = lane >> 4;          // 0..3
    const int ko = lane & 7;           // 0..7
    const int ro = lane >> 3;          // 0..7
    const int wr = w >> 1;             // wave row (0..1)
    const int wc = w & 1;              // wave col (0..1)

    if (t < 128) gpart[t] = 0.f;

    f32x4_t acc[4][4];
#pragma unroll
    for (int i = 0; i < 4; ++i)
#pragma unroll
        for (int j = 0; j < 4; ++j)
            acc[i][j] = f32x4_t{0.f, 0.f, 0.f, 0.f};

    float gacc[8];
#pragma unroll
    for (int j = 0; j < 8; ++j) gacc[j] = 0.f;

    const float*  xBase = x + (size_t)mtile * 128 * DDIM;
    const __bf16* bBase = WmT + (size_t)ntile * 128 * DDIM;   // rows = output col n

    for (int ks = 0; ks < 8; ++ks) {
        // ---- stage A (fp32 -> bf16) + gate partials ----
        const float* xK  = xBase + ks * 64;
        const float4 wg4 = *(const float4*)(Wg + ks * 64 + kq * 4);
#pragma unroll
        for (int j = 0; j < 8; ++j) {
            int r = w * 32 + j * 4 + rq;                  // 0..127 (fixed per thread/j)
            float4 xv = *(const float4*)(xK + (size_t)r * DDIM + kq * 4);
            bf16x4 v;
            v[0] = (__bf16)xv.x; v[1] = (__bf16)xv.y;
            v[2] = (__bf16)xv.z; v[3] = (__bf16)xv.w;
            int byteoff = (r * 128 + kq * 8) ^ ((r & 7) << 4);
            *(bf16x4*)((char*)As + byteoff) = v;
            gacc[j] += xv.x * wg4.x + xv.y * wg4.y + xv.z * wg4.z + xv.w * wg4.w;
        }
        // ---- stage B (bf16, already transposed) ----
#pragma unroll
        for (int j = 0; j < 4; ++j) {
            int n = w * 32 + j * 8 + ro;                  // 0..127
            bf16x8 v = *(const bf16x8*)(bBase + (size_t)n * DDIM + ks * 64 + ko * 8);
            int byteoff = (n * 128 + ko * 16) ^ ((n & 7) << 4);
            *(bf16x8*)((char*)Bs + byteoff) = v;
        }
        __syncthreads();
        // ---- MFMA ----
#pragma unroll
        for (int kk = 0; kk < 2; ++kk) {
            int kbyte = rq * 16 + kk * 64;                // lane's k-octet
            bf16x8 a[4], b[4];
#pragma unroll
            for (int mi = 0; mi < 4; ++mi) {
                int r = wr * 64 + mi * 16 + kq;
                a[mi] = *(const bf16x8*)((char*)As + ((r * 128 + kbyte) ^ ((r & 7) << 4)));
            }
#pragma unroll
            for (int ni = 0; ni < 4; ++ni) {
                int c = wc * 64 + ni * 16 + kq;
                b[ni] = *(const bf16x8*)((char*)Bs + ((c * 128 + kbyte) ^ ((c & 7) << 4)));
            }
#pragma unroll
            for (int mi = 0; mi < 4; ++mi)
#pragma unroll
                for (int ni = 0; ni < 4; ++ni)
                    acc[mi][ni] = __builtin_amdgcn_mfma_f32_16x16x32_bf16(
                        a[mi], b[ni], acc[mi][ni], 0, 0, 0);
        }
        __syncthreads();
    }

    // ---- gate: reduce per-row partials across the 16 k-lanes ----
#pragma unroll
    for (int j = 0; j < 8; ++j) {
        float p = gacc[j];
        p += __shfl_xor(p, 1);
        p += __shfl_xor(p, 2);
        p += __shfl_xor(p, 4);
        p += __shfl_xor(p, 8);
        if (kq == 0) atomicAdd(&gpart[w * 32 + j * 4 + rq], p);
    }
    __syncthreads();
    const float bgv = bgp[0];
    if (t < 128) gpart[t] = expf(gpart[t] + bgv);   // gpart now holds e_r
    __syncthreads();

    const int rowBase = mtile * 128;
    if (ntile == 0 && t < 128) {
        atomicAdd(&gsum[idx[rowBase + t]], gpart[t]);
    }

    // ---- epilogue: scatter e_r * m into out ----
#pragma unroll
    for (int mi = 0; mi < 4; ++mi) {
#pragma unroll
        for (int j = 0; j < 4; ++j) {
            int r = wr * 64 + mi * 16 + rq * 4 + j;     // C layout: row=(lane>>4)*4+j
            float e = gpart[r];
            int orow = idx[rowBase + r];
            float* op = out + (size_t)orow * DDIM + ntile * 128 + wc * 64 + kq;
#pragma unroll
            for (int ni = 0; ni < 4; ++ni) {
                atomicAdd(op + ni * 16, e * acc[mi][ni][j]);
            }
        }
    }
}

// out[s][d] = acc/(gsum+1e-10) + bm[d] * gsum/(gsum+1e-10)
__global__ void normalize_out(float* __restrict__ out,
                              const float* __restrict__ gsum,
                              const float* __restrict__ bm) {
    int i  = blockIdx.x * 256 + threadIdx.x;    // float4 index, NSEG*128 total
    int s  = i >> 7;
    int d4 = i & 127;
    float g   = gsum[s];
    float inv = 1.f / (g + 1e-10f);
    float gs  = g * inv;
    float4 v = ((float4*)out)[i];
    const float4 b = ((const float4*)bm)[d4];
    v.x = v.x * inv + b.x * gs;
    v.y = v.y * inv + b.y * gs;
    v.z = v.z * inv + b.z * gs;
    v.w = v.w * inv + b.w * gs;
    ((float4*)out)[i] = v;
}

extern "C" void kernel_launch(void* const* d_in, const int* in_sizes, int n_in,
                              void* d_out, int out_size, void* d_ws, size_t ws_size,
                              hipStream_t stream) {
    const float* x   = (const float*)d_in[0];
    const int*   idx = (const int*)d_in[1];
    const float* Wg  = (const float*)d_in[2];
    const float* bg  = (const float*)d_in[3];
    const float* Wm  = (const float*)d_in[4];
    const float* bm  = (const float*)d_in[5];

    float*  out  = (float*)d_out;
    float*  gsum = (float*)d_ws;
    __bf16* WmT  = (__bf16*)((char*)d_ws + (size_t)NSEG * sizeof(float));

    hipMemsetAsync(out, 0, (size_t)out_size * sizeof(float), stream);
    hipMemsetAsync(gsum, 0, (size_t)NSEG * sizeof(float), stream);

    prep_wmT<<<(512 * 512) / 256, 256, 0, stream>>>(Wm, WmT);

    fused_gemm<<<(NROWS / 128) * 4, 256, 0, stream>>>(x, idx, Wg, bg, WmT, out, gsum);

    normalize_out<<<(NSEG * DDIM / 4) / 256, 256, 0, stream>>>(out, gsum, bm);
}

// Round 2
// 419.850 us; speedup vs baseline: 2.2443x; 2.2443x over previous
//
#include <hip/hip_runtime.h>
#include <hip/hip_bf16.h>

#define NROWS 400000
#define DDIM  512
#define NSEG  50000

typedef __bf16 bf16x8 __attribute__((ext_vector_type(8)));
typedef float  f32x4_t __attribute__((ext_vector_type(4)));

// ---------------- counting sort: count -> scan -> scatter ----------------

__global__ void count_kernel(const int* __restrict__ idx, int* __restrict__ counts) {
    int r = blockIdx.x * 256 + threadIdx.x;
    if (r < NROWS) atomicAdd(&counts[idx[r]], 1);
}

// single block, 1024 threads: exclusive scan of counts -> offsets[NSEG+1], cursor copy
__global__ __launch_bounds__(1024)
void scan_kernel(const int* __restrict__ counts, int* __restrict__ offsets,
                 int* __restrict__ cursor) {
    __shared__ int partial[1024];
    const int t = threadIdx.x;
    const int CHUNK = 49;                       // 49*1024 >= NSEG
    int start = t * CHUNK;
    int end   = start + CHUNK; if (end > NSEG) end = NSEG;
    int s = 0;
    for (int i = start; i < end; ++i) s += counts[i];
    partial[t] = s;
    __syncthreads();
    // Hillis-Steele inclusive scan over 1024 partials
    for (int d = 1; d < 1024; d <<= 1) {
        int v = (t >= d) ? partial[t - d] : 0;
        __syncthreads();
        partial[t] += v;
        __syncthreads();
    }
    int run = (t == 0) ? 0 : partial[t - 1];
    for (int i = start; i < end; ++i) {
        offsets[i] = run; cursor[i] = run;
        run += counts[i];
    }
    if (t == 1023) offsets[NSEG] = run;         // = NROWS
}

__global__ void scatter_kernel(const int* __restrict__ idx, int* __restrict__ cursor,
                               int* __restrict__ sortedIds) {
    int r = blockIdx.x * 256 + threadIdx.x;
    if (r < NROWS) {
        int p = atomicAdd(&cursor[idx[r]], 1);
        sortedIds[p] = r;
    }
}

// ---------------- Wm [K][N] fp32 -> WmT [N][K] bf16 ----------------

__global__ void prep_wmT(const float* __restrict__ Wm, __bf16* __restrict__ WmT) {
    int o = blockIdx.x * 256 + threadIdx.x;     // o = n*512 + k
    int n = o >> 9;
    int k = o & 511;
    WmT[o] = (__bf16)Wm[k * 512 + n];
}

// ---------------- pool: one wave per segment ----------------
// px[s] = (sum_r e_r * x_r) / (gs+eps)  (bf16),  scaleB[s] = gs/(gs+eps)

__global__ __launch_bounds__(256)
void pool_kernel(const float* __restrict__ x,
                 const int* __restrict__ offsets,
                 const int* __restrict__ sortedIds,
                 const float* __restrict__ Wg,
                 const float* __restrict__ bgp,
                 __bf16* __restrict__ px,
                 float* __restrict__ scaleB) {
    const int lane = threadIdx.x & 63;
    const int s = blockIdx.x * 4 + (threadIdx.x >> 6);   // grid=12500 exact
    const float4 wg0 = *(const float4*)(Wg + lane * 8);
    const float4 wg1 = *(const float4*)(Wg + lane * 8 + 4);
    const float bg = bgp[0];
    const int beg = offsets[s], end = offsets[s + 1];

    f32x4_t acc0 = {0.f, 0.f, 0.f, 0.f}, acc1 = {0.f, 0.f, 0.f, 0.f};
    float gs = 0.f;
    for (int i = beg; i < end; ++i) {
        int r = sortedIds[i];
        const float* xr = x + (size_t)r * DDIM + lane * 8;
        float4 v0 = *(const float4*)xr;
        float4 v1 = *(const float4*)(xr + 4);
        float p = v0.x * wg0.x + v0.y * wg0.y + v0.z * wg0.z + v0.w * wg0.w
                + v1.x * wg1.x + v1.y * wg1.y + v1.z * wg1.z + v1.w * wg1.w;
        p += __shfl_xor(p, 1);  p += __shfl_xor(p, 2);  p += __shfl_xor(p, 4);
        p += __shfl_xor(p, 8);  p += __shfl_xor(p, 16); p += __shfl_xor(p, 32);
        float e = __expf(p + bg);
        gs += e;
        acc0 += e * f32x4_t{v0.x, v0.y, v0.z, v0.w};
        acc1 += e * f32x4_t{v1.x, v1.y, v1.z, v1.w};
    }
    float inv = 1.f / (gs + 1e-10f);
    bf16x8 o;
    o[0] = (__bf16)(acc0[0] * inv); o[1] = (__bf16)(acc0[1] * inv);
    o[2] = (__bf16)(acc0[2] * inv); o[3] = (__bf16)(acc0[3] * inv);
    o[4] = (__bf16)(acc1[0] * inv); o[5] = (__bf16)(acc1[1] * inv);
    o[6] = (__bf16)(acc1[2] * inv); o[7] = (__bf16)(acc1[3] * inv);
    *(bf16x8*)(px + (size_t)s * DDIM + lane * 8) = o;
    if (lane == 0) scaleB[s] = gs * inv;
}

// ---------------- GEMM: out = px @ Wm + bm*scaleB (no atomics) ----------------

__global__ __launch_bounds__(256)
void gemm_out(const __bf16* __restrict__ px,
              const __bf16* __restrict__ WmT,
              const float* __restrict__ bm,
              const float* __restrict__ scaleB,
              float* __restrict__ out) {
    __shared__ __align__(16) __bf16 As[128 * 64];
    __shared__ __align__(16) __bf16 Bs[128 * 64];

    const int t     = threadIdx.x;
    const int lane  = t & 63;
    const int w     = t >> 6;
    const int ntile = blockIdx.x & 3;
    const int mtile = blockIdx.x >> 2;

    const int kq = lane & 15;
    const int rq = lane >> 4;
    const int ko = lane & 7;
    const int ro = lane >> 3;
    const int wr = w >> 1;
    const int wc = w & 1;

    f32x4_t acc[4][4];
#pragma unroll
    for (int i = 0; i < 4; ++i)
#pragma unroll
        for (int j = 0; j < 4; ++j)
            acc[i][j] = f32x4_t{0.f, 0.f, 0.f, 0.f};

    const __bf16* bBase = WmT + (size_t)ntile * 128 * DDIM;

    for (int ks = 0; ks < 8; ++ks) {
        // stage A (px, already bf16)
#pragma unroll
        for (int j = 0; j < 4; ++j) {
            int rrow = w * 32 + j * 8 + ro;
            int grow = mtile * 128 + rrow;
            if (grow >= NSEG) grow = NSEG - 1;            // tail clamp (store guarded)
            bf16x8 v = *(const bf16x8*)(px + (size_t)grow * DDIM + ks * 64 + ko * 8);
            *(bf16x8*)((char*)As + ((rrow * 128 + ko * 16) ^ ((rrow & 7) << 4))) = v;
        }
        // stage B
#pragma unroll
        for (int j = 0; j < 4; ++j) {
            int n = w * 32 + j * 8 + ro;
            bf16x8 v = *(const bf16x8*)(bBase + (size_t)n * DDIM + ks * 64 + ko * 8);
            *(bf16x8*)((char*)Bs + ((n * 128 + ko * 16) ^ ((n & 7) << 4))) = v;
        }
        __syncthreads();
#pragma unroll
        for (int kk = 0; kk < 2; ++kk) {
            int kbyte = rq * 16 + kk * 64;
            bf16x8 a[4], b[4];
#pragma unroll
            for (int mi = 0; mi < 4; ++mi) {
                int r = wr * 64 + mi * 16 + kq;
                a[mi] = *(const bf16x8*)((char*)As + ((r * 128 + kbyte) ^ ((r & 7) << 4)));
            }
#pragma unroll
            for (int ni = 0; ni < 4; ++ni) {
                int c = wc * 64 + ni * 16 + kq;
                b[ni] = *(const bf16x8*)((char*)Bs + ((c * 128 + kbyte) ^ ((c & 7) << 4)));
            }
#pragma unroll
            for (int mi = 0; mi < 4; ++mi)
#pragma unroll
                for (int ni = 0; ni < 4; ++ni)
                    acc[mi][ni] = __builtin_amdgcn_mfma_f32_16x16x32_bf16(
                        a[mi], b[ni], acc[mi][ni], 0, 0, 0);
        }
        __syncthreads();
    }

    // epilogue: direct stores, bias term bm*scaleB
#pragma unroll
    for (int mi = 0; mi < 4; ++mi) {
#pragma unroll
        for (int j = 0; j < 4; ++j) {
            int rrow = wr * 64 + mi * 16 + rq * 4 + j;    // C layout: row=(lane>>4)*4+j
            int grow = mtile * 128 + rrow;
            if (grow < NSEG) {
                float sb = scaleB[grow];
                float* op = out + (size_t)grow * DDIM + ntile * 128 + wc * 64 + kq;
                const float* bp = bm + ntile * 128 + wc * 64 + kq;
#pragma unroll
                for (int ni = 0; ni < 4; ++ni)
                    op[ni * 16] = acc[mi][ni][j] + bp[ni * 16] * sb;
            }
        }
    }
}

extern "C" void kernel_launch(void* const* d_in, const int* in_sizes, int n_in,
                              void* d_out, int out_size, void* d_ws, size_t ws_size,
                              hipStream_t stream) {
    const float* x   = (const float*)d_in[0];
    const int*   idx = (const int*)d_in[1];
    const float* Wg  = (const float*)d_in[2];
    const float* bg  = (const float*)d_in[3];
    const float* Wm  = (const float*)d_in[4];
    const float* bm  = (const float*)d_in[5];
    float* out = (float*)d_out;

    char* W = (char*)d_ws;
    int*    counts    = (int*)   (W + 0);         // 200,000 B
    int*    offsets   = (int*)   (W + 200704);    // 200,004 B (NSEG+1)
    int*    cursor    = (int*)   (W + 401408);    // 200,000 B
    float*  scaleB    = (float*) (W + 602112);    // 200,000 B
    __bf16* WmT       = (__bf16*)(W + 802816);    // 524,288 B
    int*    sortedIds = (int*)   (W + 1327104);   // 1,600,000 B
    __bf16* px        = (__bf16*)(W + 2927104);   // 51,200,000 B

    hipMemsetAsync(counts, 0, NSEG * sizeof(int), stream);

    count_kernel<<<(NROWS + 255) / 256, 256, 0, stream>>>(idx, counts);
    scan_kernel<<<1, 1024, 0, stream>>>(counts, offsets, cursor);
    scatter_kernel<<<(NROWS + 255) / 256, 256, 0, stream>>>(idx, cursor, sortedIds);
    prep_wmT<<<(512 * 512) / 256, 256, 0, stream>>>(Wm, WmT);

    pool_kernel<<<NSEG / 4, 256, 0, stream>>>(x, offsets, sortedIds, Wg, bg, px, scaleB);

    int mtiles = (NSEG + 127) / 128;              // 391
    gemm_out<<<mtiles * 4, 256, 0, stream>>>(px, WmT, bm, scaleB, out);
}

// Round 3
// 412.076 us; speedup vs baseline: 2.2867x; 1.0189x over previous
//
#include <hip/hip_runtime.h>
#include <hip/hip_bf16.h>

#define NROWS 400000
#define DDIM  512
#define NSEG  50000

typedef __bf16 bf16x8 __attribute__((ext_vector_type(8)));
typedef float  f32x4_t __attribute__((ext_vector_type(4)));

#define GLOAD_LDS16(gsrc, ldst)                                                  \
    __builtin_amdgcn_global_load_lds(                                            \
        (const __attribute__((address_space(1))) void*)(gsrc),                   \
        (__attribute__((address_space(3))) void*)(ldst), 16, 0, 0)

// ---------------- fused: count (blocks 0..1562) + Wm transpose (blocks 1563..2586)

__global__ void count_and_prep(const int* __restrict__ idx, int* __restrict__ counts,
                               const float* __restrict__ Wm, __bf16* __restrict__ WmT) {
    int b = blockIdx.x;
    if (b < 1563) {
        int r = b * 256 + threadIdx.x;
        if (r < NROWS) atomicAdd(&counts[idx[r]], 1);
    } else {
        int o = (b - 1563) * 256 + threadIdx.x;   // o = n*512 + k, 1024 blocks
        int n = o >> 9;
        int k = o & 511;
        WmT[o] = (__bf16)Wm[k * 512 + n];
    }
}

// single block, 1024 threads: exclusive scan of counts -> offsets[NSEG+1], cursor copy
__global__ __launch_bounds__(1024)
void scan_kernel(const int* __restrict__ counts, int* __restrict__ offsets,
                 int* __restrict__ cursor) {
    __shared__ int partial[1024];
    const int t = threadIdx.x;
    const int CHUNK = 49;                       // 49*1024 >= NSEG
    int start = t * CHUNK;
    int end   = start + CHUNK; if (end > NSEG) end = NSEG;
    int s = 0;
    for (int i = start; i < end; ++i) s += counts[i];
    partial[t] = s;
    __syncthreads();
    for (int d = 1; d < 1024; d <<= 1) {
        int v = (t >= d) ? partial[t - d] : 0;
        __syncthreads();
        partial[t] += v;
        __syncthreads();
    }
    int run = (t == 0) ? 0 : partial[t - 1];
    for (int i = start; i < end; ++i) {
        offsets[i] = run; cursor[i] = run;
        run += counts[i];
    }
    if (t == 1023) offsets[NSEG] = run;
}

__global__ void scatter_kernel(const int* __restrict__ idx, int* __restrict__ cursor,
                               int* __restrict__ sortedIds) {
    int r = blockIdx.x * 256 + threadIdx.x;
    if (r < NROWS) {
        int p = atomicAdd(&cursor[idx[r]], 1);
        sortedIds[p] = r;
    }
}

// ---------------- pool: one wave per segment, 1-deep pipelined ----------------
// px[s] = (sum_r e_r * x_r) / (gs+eps)  (bf16),  scaleB[s] = gs/(gs+eps)

__global__ __launch_bounds__(256)
void pool_kernel(const float* __restrict__ x,
                 const int* __restrict__ offsets,
                 const int* __restrict__ sortedIds,
                 const float* __restrict__ Wg,
                 const float* __restrict__ bgp,
                 __bf16* __restrict__ px,
                 float* __restrict__ scaleB) {
    const int lane = threadIdx.x & 63;
    const int s = blockIdx.x * 4 + (threadIdx.x >> 6);   // grid=12500 exact
    const f32x4_t wg0 = *(const f32x4_t*)(Wg + lane * 8);
    const f32x4_t wg1 = *(const f32x4_t*)(Wg + lane * 8 + 4);
    const float bg = bgp[0];
    const int beg = offsets[s], end = offsets[s + 1];

    f32x4_t acc0 = {0.f, 0.f, 0.f, 0.f}, acc1 = {0.f, 0.f, 0.f, 0.f};
    float gs = 0.f;

    f32x4_t c0 = {0.f, 0.f, 0.f, 0.f}, c1 = c0, n0 = c0, n1 = c0;
    if (beg < end) {
        int r0 = sortedIds[beg];
        const float* xr = x + (size_t)r0 * DDIM + lane * 8;
        c0 = __builtin_nontemporal_load((const f32x4_t*)xr);
        c1 = __builtin_nontemporal_load((const f32x4_t*)(xr + 4));
    }
    for (int i = beg; i < end; ++i) {
        if (i + 1 < end) {
            int r1 = sortedIds[i + 1];
            const float* xr = x + (size_t)r1 * DDIM + lane * 8;
            n0 = __builtin_nontemporal_load((const f32x4_t*)xr);
            n1 = __builtin_nontemporal_load((const f32x4_t*)(xr + 4));
        }
        float p = c0.x * wg0.x + c0.y * wg0.y + c0.z * wg0.z + c0.w * wg0.w
                + c1.x * wg1.x + c1.y * wg1.y + c1.z * wg1.z + c1.w * wg1.w;
        p += __shfl_xor(p, 1);  p += __shfl_xor(p, 2);  p += __shfl_xor(p, 4);
        p += __shfl_xor(p, 8);  p += __shfl_xor(p, 16); p += __shfl_xor(p, 32);
        float e = __expf(p + bg);
        gs += e;
        acc0 += e * c0;
        acc1 += e * c1;
        c0 = n0; c1 = n1;
    }
    float inv = 1.f / (gs + 1e-10f);
    bf16x8 o;
    o[0] = (__bf16)(acc0.x * inv); o[1] = (__bf16)(acc0.y * inv);
    o[2] = (__bf16)(acc0.z * inv); o[3] = (__bf16)(acc0.w * inv);
    o[4] = (__bf16)(acc1.x * inv); o[5] = (__bf16)(acc1.y * inv);
    o[6] = (__bf16)(acc1.z * inv); o[7] = (__bf16)(acc1.w * inv);
    *(bf16x8*)(px + (size_t)s * DDIM + lane * 8) = o;
    if (lane == 0) scaleB[s] = gs * inv;
}

// ---------------- GEMM: out = px @ Wm + bm*scaleB ----------------
// global_load_lds staging (pre-swizzled source), 2-phase double buffer.

__global__ __launch_bounds__(256)
void gemm_out(const __bf16* __restrict__ px,
              const __bf16* __restrict__ WmT,
              const float* __restrict__ bm,
              const float* __restrict__ scaleB,
              float* __restrict__ out) {
    __shared__ __align__(16) __bf16 As[2][128 * 64];
    __shared__ __align__(16) __bf16 Bs[2][128 * 64];

    const int t     = threadIdx.x;
    const int lane  = t & 63;
    const int w     = t >> 6;
    const int ntile = blockIdx.x & 3;
    const int mtile = blockIdx.x >> 2;

    const int kq = lane & 15;
    const int rq = lane >> 4;
    const int wr = w >> 1;
    const int wc = w & 1;

    // Pre-swizzled staging sources: LDS is written LINEARLY by global_load_lds
    // (wave-uniform base + lane*16); we permute the GLOBAL source so that the
    // linear LDS image equals the XOR-swizzled layout the frag reads expect.
    const char* srcA[4];
    const char* srcB[4];
    int ldsOff[4];
#pragma unroll
    for (int q = 0; q < 4; ++q) {
        int base = w * 4096 + q * 1024;          // wave-uniform
        int L = base + lane * 16;                // this lane's LDS byte
        int r = L >> 7;                          // tile row 0..127
        int c = (L & 127) ^ ((r & 7) << 4);      // source column byte (swizzle inv)
        ldsOff[q] = base;
        int growA = mtile * 128 + r; if (growA >= NSEG) growA = NSEG - 1;
        srcA[q] = (const char*)px + (size_t)growA * 1024 + c;
        int nrow = ntile * 128 + r;
        srcB[q] = (const char*)WmT + (size_t)nrow * 1024 + c;
    }

    f32x4_t acc[4][4];
#pragma unroll
    for (int i = 0; i < 4; ++i)
#pragma unroll
        for (int j = 0; j < 4; ++j)
            acc[i][j] = f32x4_t{0.f, 0.f, 0.f, 0.f};

    auto stage = [&](int buf, int ks) {
#pragma unroll
        for (int q = 0; q < 4; ++q) {
            GLOAD_LDS16(srcA[q] + ks * 128, (char*)As[buf] + ldsOff[q]);
            GLOAD_LDS16(srcB[q] + ks * 128, (char*)Bs[buf] + ldsOff[q]);
        }
    };
    auto compute = [&](int buf) {
#pragma unroll
        for (int kk = 0; kk < 2; ++kk) {
            int kbyte = rq * 16 + kk * 64;
            bf16x8 a[4], b[4];
#pragma unroll
            for (int mi = 0; mi < 4; ++mi) {
                int r = wr * 64 + mi * 16 + kq;
                a[mi] = *(const bf16x8*)((char*)As[buf] + ((r * 128 + kbyte) ^ ((r & 7) << 4)));
            }
#pragma unroll
            for (int ni = 0; ni < 4; ++ni) {
                int c = wc * 64 + ni * 16 + kq;
                b[ni] = *(const bf16x8*)((char*)Bs[buf] + ((c * 128 + kbyte) ^ ((c & 7) << 4)));
            }
#pragma unroll
            for (int mi = 0; mi < 4; ++mi)
#pragma unroll
                for (int ni = 0; ni < 4; ++ni)
                    acc[mi][ni] = __builtin_amdgcn_mfma_f32_16x16x32_bf16(
                        a[mi], b[ni], acc[mi][ni], 0, 0, 0);
        }
    };

    // prologue
    stage(0, 0);
    asm volatile("s_waitcnt vmcnt(0)" ::: "memory");
    __builtin_amdgcn_s_barrier();
    int cur = 0;
#pragma unroll
    for (int ks = 0; ks < 7; ++ks) {
        stage(cur ^ 1, ks + 1);     // issue next tile (overlaps with MFMA below)
        compute(cur);
        asm volatile("s_waitcnt vmcnt(0)" ::: "memory");
        __builtin_amdgcn_s_barrier();
        cur ^= 1;
    }
    compute(cur);                   // last tile, no prefetch

    // epilogue: direct stores, bias term bm*scaleB
#pragma unroll
    for (int mi = 0; mi < 4; ++mi) {
#pragma unroll
        for (int j = 0; j < 4; ++j) {
            int rrow = wr * 64 + mi * 16 + rq * 4 + j;    // C layout: row=(lane>>4)*4+j
            int grow = mtile * 128 + rrow;
            if (grow < NSEG) {
                float sb = scaleB[grow];
                float* op = out + (size_t)grow * DDIM + ntile * 128 + wc * 64 + kq;
                const float* bp = bm + ntile * 128 + wc * 64 + kq;
#pragma unroll
                for (int ni = 0; ni < 4; ++ni)
                    op[ni * 16] = acc[mi][ni][j] + bp[ni * 16] * sb;
            }
        }
    }
}

extern "C" void kernel_launch(void* const* d_in, const int* in_sizes, int n_in,
                              void* d_out, int out_size, void* d_ws, size_t ws_size,
                              hipStream_t stream) {
    const float* x   = (const float*)d_in[0];
    const int*   idx = (const int*)d_in[1];
    const float* Wg  = (const float*)d_in[2];
    const float* bg  = (const float*)d_in[3];
    const float* Wm  = (const float*)d_in[4];
    const float* bm  = (const float*)d_in[5];
    float* out = (float*)d_out;

    char* W = (char*)d_ws;
    int*    counts    = (int*)   (W + 0);         // 200,000 B
    int*    offsets   = (int*)   (W + 200704);    // 200,004 B (NSEG+1)
    int*    cursor    = (int*)   (W + 401408);    // 200,000 B
    float*  scaleB    = (float*) (W + 602112);    // 200,000 B
    __bf16* WmT       = (__bf16*)(W + 802816);    // 524,288 B
    int*    sortedIds = (int*)   (W + 1327104);   // 1,600,000 B
    __bf16* px        = (__bf16*)(W + 2927104);   // 51,200,000 B

    hipMemsetAsync(counts, 0, NSEG * sizeof(int), stream);

    count_and_prep<<<1563 + 1024, 256, 0, stream>>>(idx, counts, Wm, WmT);
    scan_kernel<<<1, 1024, 0, stream>>>(counts, offsets, cursor);
    scatter_kernel<<<(NROWS + 255) / 256, 256, 0, stream>>>(idx, cursor, sortedIds);

    pool_kernel<<<NSEG / 4, 256, 0, stream>>>(x, offsets, sortedIds, Wg, bg, px, scaleB);

    int mtiles = (NSEG + 127) / 128;              // 391
    gemm_out<<<mtiles * 4, 256, 0, stream>>>(px, WmT, bm, scaleB, out);
}

// Round 4
// 328.872 us; speedup vs baseline: 2.8652x; 1.2530x over previous
//
#include <hip/hip_runtime.h>
#include <hip/hip_bf16.h>

#define NROWS 400000
#define DDIM  512
#define NSEG  50000

typedef __bf16 bf16x8 __attribute__((ext_vector_type(8)));
typedef float  f32x4_t __attribute__((ext_vector_type(4)));

#define GLOAD_LDS16(gsrc, ldst)                                                  \
    __builtin_amdgcn_global_load_lds(                                            \
        (const __attribute__((address_space(1))) void*)(gsrc),                   \
        (__attribute__((address_space(3))) void*)(ldst), 16, 0, 0)

// ---- fused: count (blocks 0..1562) + LDS-tiled Wm transpose (blocks 1563..1626)

__global__ __launch_bounds__(256)
void count_and_prep(const int* __restrict__ idx, int* __restrict__ counts,
                    const float* __restrict__ Wm, __bf16* __restrict__ WmT) {
    __shared__ float tile[64 * 65];
    int b = blockIdx.x;
    int t = threadIdx.x;
    if (b < 1563) {
        int r = b * 256 + t;
        if (r < NROWS) atomicAdd(&counts[idx[r]], 1);
    } else {
        int tb = b - 1563;                 // 0..63 -> 8x8 tiles of 64x64
        int kt = tb >> 3, nt = tb & 7;
        int cc = t & 63, rg = t >> 6;      // col, row-group
#pragma unroll
        for (int it = 0; it < 16; ++it) {
            int rr = it * 4 + rg;
            tile[rr * 65 + cc] = Wm[(size_t)(kt * 64 + rr) * 512 + nt * 64 + cc];
        }
        __syncthreads();
#pragma unroll
        for (int it = 0; it < 16; ++it) {
            int nn = it * 4 + rg;
            WmT[(size_t)(nt * 64 + nn) * 512 + kt * 64 + cc] =
                (__bf16)tile[cc * 65 + nn];
        }
    }
}

// ---- coalesced single-block scan: counts -> offsets[NSEG+1], cursor ----

__global__ __launch_bounds__(1024)
void scan_kernel(const int* __restrict__ counts, int* __restrict__ offsets,
                 int* __restrict__ cursor) {
    __shared__ int waveSums[16];
    const int t = threadIdx.x;
    const int lane = t & 63;
    const int w = t >> 6;
    const int base = w * 3125;             // 16*3125 = 50000 exact
    const int end  = base + 3125;

    // pass 1: per-wave sum, coalesced
    int s = 0;
    for (int j = base + lane; j < end; j += 64) s += counts[j];
#pragma unroll
    for (int d = 1; d < 64; d <<= 1) s += __shfl_xor(s, d);
    if (lane == 0) waveSums[w] = s;
    __syncthreads();
    if (t == 0) {
        int run = 0;
#pragma unroll
        for (int i = 0; i < 16; ++i) { int v = waveSums[i]; waveSums[i] = run; run += v; }
    }
    __syncthreads();
    int run = waveSums[w];

    // pass 2: coalesced loads, wave shuffle-prefix, coalesced stores
    for (int j0 = base; j0 < end; j0 += 64) {
        int j = j0 + lane;
        int c = (j < end) ? counts[j] : 0;
        int inc = c;
#pragma unroll
        for (int d = 1; d < 64; d <<= 1) {
            int v = __shfl_up(inc, d);
            if (lane >= d) inc += v;
        }
        int exc = run + inc - c;
        if (j < end) { offsets[j] = exc; cursor[j] = exc; }
        run += __shfl(inc, 63);
    }
    if (t == 1023) offsets[NSEG] = NROWS;
}

__global__ void scatter_kernel(const int* __restrict__ idx, int* __restrict__ cursor,
                               int* __restrict__ sortedIds) {
    int r = blockIdx.x * 256 + threadIdx.x;
    if (r < NROWS) {
        int p = atomicAdd(&cursor[idx[r]], 1);
        sortedIds[p] = r;
    }
}

// ---- pool: one wave per segment, 2 rows in flight ----

__global__ __launch_bounds__(256)
void pool_kernel(const float* __restrict__ x,
                 const int* __restrict__ offsets,
                 const int* __restrict__ sortedIds,
                 const float* __restrict__ Wg,
                 const float* __restrict__ bgp,
                 __bf16* __restrict__ px,
                 float* __restrict__ scaleB) {
    const int lane = threadIdx.x & 63;
    const int s = blockIdx.x * 4 + (threadIdx.x >> 6);
    const f32x4_t wg0 = *(const f32x4_t*)(Wg + lane * 8);
    const f32x4_t wg1 = *(const f32x4_t*)(Wg + lane * 8 + 4);
    const float bg = bgp[0];
    const int beg = offsets[s];
    const int n   = offsets[s + 1] - beg;
    const int* sid = sortedIds + beg;

    f32x4_t acc0 = {0.f, 0.f, 0.f, 0.f}, acc1 = acc0;
    float gs = 0.f;

    f32x4_t A0 = acc0, A1 = acc0, B0 = acc0, B1 = acc0;

#define LOADR(k, u0, u1)                                                        \
    {   const float* xr = x + (size_t)sid[k] * DDIM + lane * 8;                 \
        u0 = __builtin_nontemporal_load((const f32x4_t*)xr);                    \
        u1 = __builtin_nontemporal_load((const f32x4_t*)(xr + 4)); }
#define COMPR(u0, u1)                                                           \
    {   float p = u0.x * wg0.x + u0.y * wg0.y + u0.z * wg0.z + u0.w * wg0.w     \
                + u1.x * wg1.x + u1.y * wg1.y + u1.z * wg1.z + u1.w * wg1.w;    \
        p += __shfl_xor(p, 1);  p += __shfl_xor(p, 2);  p += __shfl_xor(p, 4);  \
        p += __shfl_xor(p, 8);  p += __shfl_xor(p, 16); p += __shfl_xor(p, 32); \
        float e = __expf(p + bg);                                               \
        gs += e; acc0 += e * u0; acc1 += e * u1; }

    if (n > 0) LOADR(0, A0, A1);
    if (n > 1) LOADR(1, B0, B1);
    int k = 0;
    for (; k + 2 < n; k += 2) {
        f32x4_t C0 = acc0, C1 = acc0, D0 = acc0, D1 = acc0;
        LOADR(k + 2, C0, C1);
        if (k + 3 < n) LOADR(k + 3, D0, D1);
        COMPR(A0, A1);
        COMPR(B0, B1);
        A0 = C0; A1 = C1; B0 = D0; B1 = D1;
    }
    if (k < n)     COMPR(A0, A1);
    if (k + 1 < n) COMPR(B0, B1);
#undef LOADR
#undef COMPR

    float inv = 1.f / (gs + 1e-10f);
    bf16x8 o;
    o[0] = (__bf16)(acc0.x * inv); o[1] = (__bf16)(acc0.y * inv);
    o[2] = (__bf16)(acc0.z * inv); o[3] = (__bf16)(acc0.w * inv);
    o[4] = (__bf16)(acc1.x * inv); o[5] = (__bf16)(acc1.y * inv);
    o[6] = (__bf16)(acc1.z * inv); o[7] = (__bf16)(acc1.w * inv);
    *(bf16x8*)(px + (size_t)s * DDIM + lane * 8) = o;
    if (lane == 0) scaleB[s] = gs * inv;
}

// ---- GEMM: out = px @ Wm + bm*scaleB — m97 single-buffer structure ----

__global__ __launch_bounds__(256)
void gemm_out(const __bf16* __restrict__ px,
              const __bf16* __restrict__ WmT,
              const float* __restrict__ bm,
              const float* __restrict__ scaleB,
              float* __restrict__ out) {
    __shared__ __align__(16) __bf16 As[128 * 64];
    __shared__ __align__(16) __bf16 Bs[128 * 64];

    const int t     = threadIdx.x;
    const int lane  = t & 63;
    const int w     = t >> 6;
    const int ntile = blockIdx.x & 3;
    const int mtile = blockIdx.x >> 2;

    const int kq = lane & 15;
    const int rq = lane >> 4;
    const int wr = w >> 1;
    const int wc = w & 1;

    // pre-swizzled global sources; LDS dest stays linear (global_load_lds rule)
    const char* srcA[4];
    const char* srcB[4];
    int ldsOff[4];
#pragma unroll
    for (int q = 0; q < 4; ++q) {
        int base = w * 4096 + q * 1024;
        int L = base + lane * 16;
        int r = L >> 7;
        int c = (L & 127) ^ ((r & 7) << 4);
        ldsOff[q] = base;
        int growA = mtile * 128 + r; if (growA >= NSEG) growA = NSEG - 1;
        srcA[q] = (const char*)px + (size_t)growA * 1024 + c;
        srcB[q] = (const char*)WmT + (size_t)(ntile * 128 + r) * 1024 + c;
    }

    f32x4_t acc[4][4];
#pragma unroll
    for (int i = 0; i < 4; ++i)
#pragma unroll
        for (int j = 0; j < 4; ++j)
            acc[i][j] = f32x4_t{0.f, 0.f, 0.f, 0.f};

    for (int ks = 0; ks < 8; ++ks) {
#pragma unroll
        for (int q = 0; q < 4; ++q) {
            GLOAD_LDS16(srcA[q] + ks * 128, (char*)As + ldsOff[q]);
            GLOAD_LDS16(srcB[q] + ks * 128, (char*)Bs + ldsOff[q]);
        }
        asm volatile("s_waitcnt vmcnt(0)" ::: "memory");
        __builtin_amdgcn_s_barrier();
#pragma unroll
        for (int kk = 0; kk < 2; ++kk) {
            int kbyte = rq * 16 + kk * 64;
            bf16x8 a[4], b[4];
#pragma unroll
            for (int mi = 0; mi < 4; ++mi) {
                int r = wr * 64 + mi * 16 + kq;
                a[mi] = *(const bf16x8*)((char*)As + ((r * 128 + kbyte) ^ ((r & 7) << 4)));
            }
#pragma unroll
            for (int ni = 0; ni < 4; ++ni) {
                int c = wc * 64 + ni * 16 + kq;
                b[ni] = *(const bf16x8*)((char*)Bs + ((c * 128 + kbyte) ^ ((c & 7) << 4)));
            }
#pragma unroll
            for (int mi = 0; mi < 4; ++mi)
#pragma unroll
                for (int ni = 0; ni < 4; ++ni)
                    acc[mi][ni] = __builtin_amdgcn_mfma_f32_16x16x32_bf16(
                        a[mi], b[ni], acc[mi][ni], 0, 0, 0);
        }
        __builtin_amdgcn_s_barrier();
    }

#pragma unroll
    for (int mi = 0; mi < 4; ++mi) {
#pragma unroll
        for (int j = 0; j < 4; ++j) {
            int rrow = wr * 64 + mi * 16 + rq * 4 + j;
            int grow = mtile * 128 + rrow;
            if (grow < NSEG) {
                float sb = scaleB[grow];
                float* op = out + (size_t)grow * DDIM + ntile * 128 + wc * 64 + kq;
                const float* bp = bm + ntile * 128 + wc * 64 + kq;
#pragma unroll
                for (int ni = 0; ni < 4; ++ni)
                    op[ni * 16] = acc[mi][ni][j] + bp[ni * 16] * sb;
            }
        }
    }
}

extern "C" void kernel_launch(void* const* d_in, const int* in_sizes, int n_in,
                              void* d_out, int out_size, void* d_ws, size_t ws_size,
                              hipStream_t stream) {
    const float* x   = (const float*)d_in[0];
    const int*   idx = (const int*)d_in[1];
    const float* Wg  = (const float*)d_in[2];
    const float* bg  = (const float*)d_in[3];
    const float* Wm  = (const float*)d_in[4];
    const float* bm  = (const float*)d_in[5];
    float* out = (float*)d_out;

    char* W = (char*)d_ws;
    int*    counts    = (int*)   (W + 0);
    int*    offsets   = (int*)   (W + 200704);
    int*    cursor    = (int*)   (W + 401408);
    float*  scaleB    = (float*) (W + 602112);
    __bf16* WmT       = (__bf16*)(W + 802816);
    int*    sortedIds = (int*)   (W + 1327104);
    __bf16* px        = (__bf16*)(W + 2927104);

    hipMemsetAsync(counts, 0, NSEG * sizeof(int), stream);

    count_and_prep<<<1563 + 64, 256, 0, stream>>>(idx, counts, Wm, WmT);
    scan_kernel<<<1, 1024, 0, stream>>>(counts, offsets, cursor);
    scatter_kernel<<<(NROWS + 255) / 256, 256, 0, stream>>>(idx, cursor, sortedIds);

    pool_kernel<<<NSEG / 4, 256, 0, stream>>>(x, offsets, sortedIds, Wg, bg, px, scaleB);

    int mtiles = (NSEG + 127) / 128;              // 391
    gemm_out<<<mtiles * 4, 256, 0, stream>>>(px, WmT, bm, scaleB, out);
}

// Round 5
// 327.323 us; speedup vs baseline: 2.8787x; 1.0047x over previous
//
#include <hip/hip_runtime.h>
#include <hip/hip_bf16.h>

#define NROWS 400000
#define DDIM  512
#define NSEG  50000

typedef __bf16 bf16x8 __attribute__((ext_vector_type(8)));
typedef float  f32x4_t __attribute__((ext_vector_type(4)));

#define GLOAD_LDS16(gsrc, ldst)                                                  \
    __builtin_amdgcn_global_load_lds(                                            \
        (const __attribute__((address_space(1))) void*)(gsrc),                   \
        (__attribute__((address_space(3))) void*)(ldst), 16, 0, 0)

// ---- fused: count (blocks 0..1562) + LDS-tiled Wm transpose (blocks 1563..1626)

__global__ __launch_bounds__(256)
void count_and_prep(const int* __restrict__ idx, int* __restrict__ counts,
                    const float* __restrict__ Wm, __bf16* __restrict__ WmT) {
    __shared__ float tile[64 * 65];
    int b = blockIdx.x;
    int t = threadIdx.x;
    if (b < 1563) {
        int r = b * 256 + t;
        if (r < NROWS) atomicAdd(&counts[idx[r]], 1);
    } else {
        int tb = b - 1563;                 // 0..63 -> 8x8 tiles of 64x64
        int kt = tb >> 3, nt = tb & 7;
        int cc = t & 63, rg = t >> 6;
#pragma unroll
        for (int it = 0; it < 16; ++it) {
            int rr = it * 4 + rg;
            tile[rr * 65 + cc] = Wm[(size_t)(kt * 64 + rr) * 512 + nt * 64 + cc];
        }
        __syncthreads();
#pragma unroll
        for (int it = 0; it < 16; ++it) {
            int nn = it * 4 + rg;
            WmT[(size_t)(nt * 64 + nn) * 512 + kt * 64 + cc] =
                (__bf16)tile[cc * 65 + nn];
        }
    }
}

// ---- coalesced single-block scan: counts -> offsets[NSEG+1], cursor ----

__global__ __launch_bounds__(1024)
void scan_kernel(const int* __restrict__ counts, int* __restrict__ offsets,
                 int* __restrict__ cursor) {
    __shared__ int waveSums[16];
    const int t = threadIdx.x;
    const int lane = t & 63;
    const int w = t >> 6;
    const int base = w * 3125;             // 16*3125 = 50000 exact
    const int end  = base + 3125;

    int s = 0;
    for (int j = base + lane; j < end; j += 64) s += counts[j];
#pragma unroll
    for (int d = 1; d < 64; d <<= 1) s += __shfl_xor(s, d);
    if (lane == 0) waveSums[w] = s;
    __syncthreads();
    if (t == 0) {
        int run = 0;
#pragma unroll
        for (int i = 0; i < 16; ++i) { int v = waveSums[i]; waveSums[i] = run; run += v; }
    }
    __syncthreads();
    int run = waveSums[w];

    for (int j0 = base; j0 < end; j0 += 64) {
        int j = j0 + lane;
        int c = (j < end) ? counts[j] : 0;
        int inc = c;
#pragma unroll
        for (int d = 1; d < 64; d <<= 1) {
            int v = __shfl_up(inc, d);
            if (lane >= d) inc += v;
        }
        int exc = run + inc - c;
        if (j < end) { offsets[j] = exc; cursor[j] = exc; }
        run += __shfl(inc, 63);
    }
    if (t == 1023) offsets[NSEG] = NROWS;
}

__global__ void scatter_kernel(const int* __restrict__ idx, int* __restrict__ cursor,
                               int* __restrict__ sortedIds) {
    int r = blockIdx.x * 256 + threadIdx.x;
    if (r < NROWS) {
        int p = atomicAdd(&cursor[idx[r]], 1);
        sortedIds[p] = r;
    }
}

// ---- pool: one wave per segment, 4 rows in flight ----

__global__ __launch_bounds__(256)
void pool_kernel(const float* __restrict__ x,
                 const int* __restrict__ offsets,
                 const int* __restrict__ sortedIds,
                 const float* __restrict__ Wg,
                 const float* __restrict__ bgp,
                 __bf16* __restrict__ px,
                 float* __restrict__ scaleB) {
    const int lane = threadIdx.x & 63;
    const int s = blockIdx.x * 4 + (threadIdx.x >> 6);
    const f32x4_t wg0 = *(const f32x4_t*)(Wg + lane * 8);
    const f32x4_t wg1 = *(const f32x4_t*)(Wg + lane * 8 + 4);
    const float bg = bgp[0];
    const int beg = offsets[s];
    const int n   = offsets[s + 1] - beg;
    const int* sid = sortedIds + beg;

    f32x4_t acc0 = {0.f, 0.f, 0.f, 0.f}, acc1 = acc0;
    float gs = 0.f;

    f32x4_t r0a = acc0, r0b = acc0, r1a = acc0, r1b = acc0;
    f32x4_t r2a = acc0, r2b = acc0, r3a = acc0, r3b = acc0;

#define LOADR(k, u0, u1)                                                        \
    {   const float* xr = x + (size_t)sid[k] * DDIM + lane * 8;                 \
        u0 = __builtin_nontemporal_load((const f32x4_t*)xr);                    \
        u1 = __builtin_nontemporal_load((const f32x4_t*)(xr + 4)); }
#define COMPR(u0, u1)                                                           \
    {   float p = u0.x * wg0.x + u0.y * wg0.y + u0.z * wg0.z + u0.w * wg0.w     \
                + u1.x * wg1.x + u1.y * wg1.y + u1.z * wg1.z + u1.w * wg1.w;    \
        p += __shfl_xor(p, 1);  p += __shfl_xor(p, 2);  p += __shfl_xor(p, 4);  \
        p += __shfl_xor(p, 8);  p += __shfl_xor(p, 16); p += __shfl_xor(p, 32); \
        float e = __expf(p + bg);                                               \
        gs += e; acc0 += e * u0; acc1 += e * u1; }

    if (n > 0) LOADR(0, r0a, r0b);
    if (n > 1) LOADR(1, r1a, r1b);
    if (n > 2) LOADR(2, r2a, r2b);
    if (n > 3) LOADR(3, r3a, r3b);

    int k = 0;
    for (; k + 8 <= n; k += 4) {
        COMPR(r0a, r0b); LOADR(k + 4, r0a, r0b);
        COMPR(r1a, r1b); LOADR(k + 5, r1a, r1b);
        COMPR(r2a, r2b); LOADR(k + 6, r2a, r2b);
        COMPR(r3a, r3b); LOADR(k + 7, r3a, r3b);
    }
    {
        int rem = n - k;                   // 0..7
        if (rem > 0) COMPR(r0a, r0b);
        if (rem > 4) LOADR(k + 4, r0a, r0b);
        if (rem > 1) COMPR(r1a, r1b);
        if (rem > 5) LOADR(k + 5, r1a, r1b);
        if (rem > 2) COMPR(r2a, r2b);
        if (rem > 6) LOADR(k + 6, r2a, r2b);
        if (rem > 3) COMPR(r3a, r3b);
        if (rem > 4) COMPR(r0a, r0b);
        if (rem > 5) COMPR(r1a, r1b);
        if (rem > 6) COMPR(r2a, r2b);
    }
#undef LOADR
#undef COMPR

    float inv = 1.f / (gs + 1e-10f);
    bf16x8 o;
    o[0] = (__bf16)(acc0.x * inv); o[1] = (__bf16)(acc0.y * inv);
    o[2] = (__bf16)(acc0.z * inv); o[3] = (__bf16)(acc0.w * inv);
    o[4] = (__bf16)(acc1.x * inv); o[5] = (__bf16)(acc1.y * inv);
    o[6] = (__bf16)(acc1.z * inv); o[7] = (__bf16)(acc1.w * inv);
    *(bf16x8*)(px + (size_t)s * DDIM + lane * 8) = o;
    if (lane == 0) scaleB[s] = gs * inv;
}

// ---- GEMM: out = px @ Wm + bm*scaleB — m97 single-buffer structure ----

__global__ __launch_bounds__(256)
void gemm_out(const __bf16* __restrict__ px,
              const __bf16* __restrict__ WmT,
              const float* __restrict__ bm,
              const float* __restrict__ scaleB,
              float* __restrict__ out) {
    __shared__ __align__(16) __bf16 As[128 * 64];
    __shared__ __align__(16) __bf16 Bs[128 * 64];

    const int t     = threadIdx.x;
    const int lane  = t & 63;
    const int w     = t >> 6;
    const int ntile = blockIdx.x & 3;
    const int mtile = blockIdx.x >> 2;

    const int kq = lane & 15;
    const int rq = lane >> 4;
    const int wr = w >> 1;
    const int wc = w & 1;

    const char* srcA[4];
    const char* srcB[4];
    int ldsOff[4];
#pragma unroll
    for (int q = 0; q < 4; ++q) {
        int base = w * 4096 + q * 1024;
        int L = base + lane * 16;
        int r = L >> 7;
        int c = (L & 127) ^ ((r & 7) << 4);
        ldsOff[q] = base;
        int growA = mtile * 128 + r; if (growA >= NSEG) growA = NSEG - 1;
        srcA[q] = (const char*)px + (size_t)growA * 1024 + c;
        srcB[q] = (const char*)WmT + (size_t)(ntile * 128 + r) * 1024 + c;
    }

    f32x4_t acc[4][4];
#pragma unroll
    for (int i = 0; i < 4; ++i)
#pragma unroll
        for (int j = 0; j < 4; ++j)
            acc[i][j] = f32x4_t{0.f, 0.f, 0.f, 0.f};

    for (int ks = 0; ks < 8; ++ks) {
#pragma unroll
        for (int q = 0; q < 4; ++q) {
            GLOAD_LDS16(srcA[q] + ks * 128, (char*)As + ldsOff[q]);
            GLOAD_LDS16(srcB[q] + ks * 128, (char*)Bs + ldsOff[q]);
        }
        asm volatile("s_waitcnt vmcnt(0)" ::: "memory");
        __builtin_amdgcn_s_barrier();
#pragma unroll
        for (int kk = 0; kk < 2; ++kk) {
            int kbyte = rq * 16 + kk * 64;
            bf16x8 a[4], b[4];
#pragma unroll
            for (int mi = 0; mi < 4; ++mi) {
                int r = wr * 64 + mi * 16 + kq;
                a[mi] = *(const bf16x8*)((char*)As + ((r * 128 + kbyte) ^ ((r & 7) << 4)));
            }
#pragma unroll
            for (int ni = 0; ni < 4; ++ni) {
                int c = wc * 64 + ni * 16 + kq;
                b[ni] = *(const bf16x8*)((char*)Bs + ((c * 128 + kbyte) ^ ((c & 7) << 4)));
            }
#pragma unroll
            for (int mi = 0; mi < 4; ++mi)
#pragma unroll
                for (int ni = 0; ni < 4; ++ni)
                    acc[mi][ni] = __builtin_amdgcn_mfma_f32_16x16x32_bf16(
                        a[mi], b[ni], acc[mi][ni], 0, 0, 0);
        }
        __builtin_amdgcn_s_barrier();
    }

#pragma unroll
    for (int mi = 0; mi < 4; ++mi) {
#pragma unroll
        for (int j = 0; j < 4; ++j) {
            int rrow = wr * 64 + mi * 16 + rq * 4 + j;
            int grow = mtile * 128 + rrow;
            if (grow < NSEG) {
                float sb = scaleB[grow];
                float* op = out + (size_t)grow * DDIM + ntile * 128 + wc * 64 + kq;
                const float* bp = bm + ntile * 128 + wc * 64 + kq;
#pragma unroll
                for (int ni = 0; ni < 4; ++ni)
                    __builtin_nontemporal_store(acc[mi][ni][j] + bp[ni * 16] * sb,
                                                op + ni * 16);
            }
        }
    }
}

extern "C" void kernel_launch(void* const* d_in, const int* in_sizes, int n_in,
                              void* d_out, int out_size, void* d_ws, size_t ws_size,
                              hipStream_t stream) {
    const float* x   = (const float*)d_in[0];
    const int*   idx = (const int*)d_in[1];
    const float* Wg  = (const float*)d_in[2];
    const float* bg  = (const float*)d_in[3];
    const float* Wm  = (const float*)d_in[4];
    const float* bm  = (const float*)d_in[5];
    float* out = (float*)d_out;

    char* W = (char*)d_ws;
    int*    counts    = (int*)   (W + 0);
    int*    offsets   = (int*)   (W + 200704);
    int*    cursor    = (int*)   (W + 401408);
    float*  scaleB    = (float*) (W + 602112);
    __bf16* WmT       = (__bf16*)(W + 802816);
    int*    sortedIds = (int*)   (W + 1327104);
    __bf16* px        = (__bf16*)(W + 2927104);

    hipMemsetAsync(counts, 0, NSEG * sizeof(int), stream);

    count_and_prep<<<1563 + 64, 256, 0, stream>>>(idx, counts, Wm, WmT);
    scan_kernel<<<1, 1024, 0, stream>>>(counts, offsets, cursor);
    scatter_kernel<<<(NROWS + 255) / 256, 256, 0, stream>>>(idx, cursor, sortedIds);

    pool_kernel<<<NSEG / 4, 256, 0, stream>>>(x, offsets, sortedIds, Wg, bg, px, scaleB);

    int mtiles = (NSEG + 127) / 128;              // 391
    gemm_out<<<mtiles * 4, 256, 0, stream>>>(px, WmT, bm, scaleB, out);
}